// Round 1
// baseline (823.731 us; speedup 1.0000x reference)
//
#include <hip/hip_runtime.h>
#include <math.h>

#define Bn 4096
#define Dn 64
#define Kn 256
#define DKn (Dn * Kn)            // 16384
#define DBn ((size_t)Dn * Bn)    // 262144
#define PARTS 8
#define BPART (Bn / PARTS)       // 512
#define NBT (Bn / 64)            // 64

// scratch layout inside d_out (floats). All consumed before K5 overwrites d_out.
#define SP_OFF 0                                   // Sp[K][D][NBT]   = 1,048,576
#define CP_OFF (Kn * Dn * NBT)                     // covp[K][PARTS][D][D] = 8,388,608
#define MU_OFF (CP_OFF + Kn * PARTS * Dn * Dn)     // mu[K][D] = 16,384
#define WT_OFF (MU_OFF + Kn * Dn)                  // wt[K][e][d] (= Linv[d][e]) = 1,048,576

// ---------------- K1: transpose x[B,D,K] -> xt[K,D,B], fused partial sums ----
__global__ __launch_bounds__(256) void k_transpose_in(
    const float* __restrict__ x, float* __restrict__ xt, float* __restrict__ Sp) {
  __shared__ float tile[64][65];
  const int b0 = blockIdx.x * 64;
  const int k0 = blockIdx.y * 64;
  const int d = blockIdx.z;
  const int l = threadIdx.x & 63;
  const int w = threadIdx.x >> 6;
#pragma unroll
  for (int i = 0; i < 16; ++i) {
    const int br = i * 4 + w;
    tile[br][l] = x[(size_t)(b0 + br) * DKn + (size_t)d * Kn + k0 + l];
  }
  __syncthreads();
  const int bt = blockIdx.x;
#pragma unroll
  for (int i = 0; i < 16; ++i) {
    const int kk = i * 4 + w;
    const float v = tile[l][kk];
    xt[(size_t)(k0 + kk) * DBn + (size_t)d * Bn + b0 + l] = v;
    float s = v;
#pragma unroll
    for (int off = 32; off > 0; off >>= 1) s += __shfl_xor(s, off, 64);
    if (l == 0) Sp[(size_t)(k0 + kk) * (Dn * NBT) + d * NBT + bt] = s;
  }
}

// ---------------- K2: partial raw second moments P = sum_b x x^T -------------
__global__ __launch_bounds__(64) void k_cov(
    const float* __restrict__ xt, float* __restrict__ covp) {
  __shared__ float xs[64][68];
  const int part = blockIdx.x;
  const int k = blockIdx.y;
  const int l = threadIdx.x;
  const int ty = l >> 3, tx = l & 7;
  const int c4 = l & 15, r4 = l >> 4;
  const float* xk = xt + (size_t)k * DBn;
  float acc[8][8];
#pragma unroll
  for (int i = 0; i < 8; ++i)
#pragma unroll
    for (int j = 0; j < 8; ++j) acc[i][j] = 0.f;

  for (int t = 0; t < BPART / 64; ++t) {
    const size_t boff = (size_t)part * BPART + (size_t)t * 64;
    __syncthreads();
#pragma unroll
    for (int u = 0; u < 16; ++u) {
      const int row = u * 4 + r4;
      const float4 v = *(const float4*)&xk[(size_t)row * Bn + boff + c4 * 4];
      *(float4*)&xs[row][c4 * 4] = v;
    }
    __syncthreads();
#pragma unroll
    for (int bb = 0; bb < 64; bb += 4) {
      float4 av[8], bv[8];
#pragma unroll
      for (int i = 0; i < 8; ++i) av[i] = *(const float4*)&xs[8 * ty + i][bb];
#pragma unroll
      for (int j = 0; j < 8; ++j) bv[j] = *(const float4*)&xs[8 * tx + j][bb];
#pragma unroll
      for (int i = 0; i < 8; ++i)
#pragma unroll
        for (int j = 0; j < 8; ++j) {
          acc[i][j] += av[i].x * bv[j].x;
          acc[i][j] += av[i].y * bv[j].y;
          acc[i][j] += av[i].z * bv[j].z;
          acc[i][j] += av[i].w * bv[j].w;
        }
    }
  }
  float* cp = covp + (size_t)k * (PARTS * Dn * Dn) + (size_t)part * (Dn * Dn);
#pragma unroll
  for (int i = 0; i < 8; ++i)
#pragma unroll
    for (int j = 0; j < 8; j += 4) {
      float4 v = make_float4(acc[i][j], acc[i][j + 1], acc[i][j + 2], acc[i][j + 3]);
      *(float4*)&cp[(8 * ty + i) * Dn + 8 * tx + j] = v;
    }
}

// ---------------- K3: cov -> Cholesky -> Linv^T, mu --------------------------
__global__ __launch_bounds__(64) void k_chol(
    const float* __restrict__ covp, const float* __restrict__ Sp,
    float* __restrict__ mu, float* __restrict__ wt) {
  __shared__ float a[64][65];
  __shared__ float mus[64];
  __shared__ float col[64];
  __shared__ float diag;
  const int k = blockIdx.x;
  const int tid = threadIdx.x;

  // mean
  float s = 0.f;
  const float* sp = Sp + (size_t)k * (Dn * NBT) + tid * NBT;
  for (int t = 0; t < NBT; ++t) s += sp[t];
  const float m = s * (1.f / (float)Bn);
  mus[tid] = m;
  mu[k * Dn + tid] = m;
  __syncthreads();

  // cov = (P - B mu mu^T) / (B-1) + eps*I
  const float* cp = covp + (size_t)k * (PARTS * Dn * Dn);
  for (int idx = tid; idx < Dn * Dn; idx += 64) {
    float p = 0.f;
    for (int q = 0; q < PARTS; ++q) p += cp[q * Dn * Dn + idx];
    const int dd = idx >> 6, e = idx & 63;
    float c = (p - (float)Bn * mus[dd] * mus[e]) * (1.f / (float)(Bn - 1));
    if (dd == e) c += 1e-4f;
    a[dd][e] = c;
  }
  __syncthreads();

  // Cholesky (right-looking, one thread per row)
  for (int j = 0; j < 64; ++j) {
    if (tid == j) diag = sqrtf(a[j][j]);
    __syncthreads();
    const float ljj = diag;
    float lij = 0.f;
    if (tid == j) a[j][j] = ljj;
    if (tid > j) {
      lij = a[tid][j] / ljj;
      a[tid][j] = lij;
      col[tid] = lij;
    }
    __syncthreads();
    if (tid > j) {
      for (int e = j + 1; e <= tid; ++e) a[tid][e] -= lij * col[e];
    }
    __syncthreads();
  }

  // invert: thread c solves L w = e_c (fully unrolled -> wv stays in registers)
  float wv[64];
#pragma unroll
  for (int i = 0; i < 64; ++i) wv[i] = 0.f;
#pragma unroll
  for (int i = 0; i < 64; ++i) {
    float s2 = (i == tid) ? 1.f : 0.f;
#pragma unroll
    for (int j = 0; j < i; ++j) s2 -= a[i][j] * wv[j];
    wv[i] = (i >= tid) ? s2 / a[i][i] : 0.f;
  }
  // wt[k][c][i] = Linv[i][c]
  float* wk = wt + (size_t)k * (Dn * Dn) + tid * Dn;
#pragma unroll
  for (int i = 0; i < 64; ++i) wk[i] = wv[i];
}

// ---------------- K4: Z = Linv (x - mu), in-place over xt --------------------
__global__ __launch_bounds__(64) void k_solve(
    float* __restrict__ xt, const float* __restrict__ wt, const float* __restrict__ mu) {
  __shared__ float wsh[64][68];  // wsh[e][d] = Linv[d][e]
  __shared__ float xsh[64][68];  // xsh[e][b]
  const int b0 = blockIdx.x * 64;
  const int k = blockIdx.y;
  const int l = threadIdx.x;
  const int c4 = l & 15, r4 = l >> 4;
  const float* wk = wt + (size_t)k * (Dn * Dn);
  float* xk = xt + (size_t)k * DBn;
#pragma unroll
  for (int u = 0; u < 16; ++u) {
    const int row = u * 4 + r4;
    *(float4*)&wsh[row][c4 * 4] = *(const float4*)&wk[row * Dn + c4 * 4];
    float4 v = *(const float4*)&xk[(size_t)row * Bn + b0 + c4 * 4];
    const float mr = mu[k * Dn + row];
    v.x -= mr; v.y -= mr; v.z -= mr; v.w -= mr;
    *(float4*)&xsh[row][c4 * 4] = v;
  }
  __syncthreads();
  const int ty = l >> 3, tx = l & 7;
  float acc[8][8];
#pragma unroll
  for (int i = 0; i < 8; ++i)
#pragma unroll
    for (int j = 0; j < 8; ++j) acc[i][j] = 0.f;
#pragma unroll
  for (int e = 0; e < 64; ++e) {
    const float4 w0 = *(const float4*)&wsh[e][8 * ty];
    const float4 w1 = *(const float4*)&wsh[e][8 * ty + 4];
    const float4 x0 = *(const float4*)&xsh[e][8 * tx];
    const float4 x1 = *(const float4*)&xsh[e][8 * tx + 4];
    const float wa[8] = {w0.x, w0.y, w0.z, w0.w, w1.x, w1.y, w1.z, w1.w};
    const float xb[8] = {x0.x, x0.y, x0.z, x0.w, x1.x, x1.y, x1.z, x1.w};
#pragma unroll
    for (int i = 0; i < 8; ++i)
#pragma unroll
      for (int j = 0; j < 8; ++j) acc[i][j] += wa[i] * xb[j];
  }
#pragma unroll
  for (int i = 0; i < 8; ++i)
#pragma unroll
    for (int j = 0; j < 8; j += 4) {
      float4 v = make_float4(acc[i][j], acc[i][j + 1], acc[i][j + 2], acc[i][j + 3]);
      *(float4*)&xk[(size_t)(8 * ty + i) * Bn + b0 + 8 * tx + j] = v;
    }
}

// ---------------- K5: transpose zt[K,D,B] -> out[B,D,K] ----------------------
__global__ __launch_bounds__(256) void k_transpose_out(
    const float* __restrict__ zt, float* __restrict__ out) {
  __shared__ float tile[64][65];
  const int b0 = blockIdx.x * 64;
  const int k0 = blockIdx.y * 64;
  const int d = blockIdx.z;
  const int l = threadIdx.x & 63;
  const int w = threadIdx.x >> 6;
#pragma unroll
  for (int i = 0; i < 16; ++i) {
    const int kk = i * 4 + w;
    tile[kk][l] = zt[(size_t)(k0 + kk) * DBn + (size_t)d * Bn + b0 + l];
  }
  __syncthreads();
#pragma unroll
  for (int i = 0; i < 16; ++i) {
    const int br = i * 4 + w;
    out[(size_t)(b0 + br) * DKn + (size_t)d * Kn + k0 + l] = tile[l][br];
  }
}

extern "C" void kernel_launch(void* const* d_in, const int* in_sizes, int n_in,
                              void* d_out, int out_size, void* d_ws, size_t ws_size,
                              hipStream_t stream) {
  (void)in_sizes; (void)n_in; (void)out_size;
  const float* x = (const float*)d_in[0];
  float* out = (float*)d_out;
  float* xt = (float*)d_ws;  // [K][D][B] fp32, 256 MiB
  if (ws_size < sizeof(float) * (size_t)Kn * DBn) return;  // need 256 MiB scratch

  float* Sp = out + SP_OFF;
  float* covp = out + CP_OFF;
  float* mub = out + MU_OFF;
  float* wtb = out + WT_OFF;

  k_transpose_in<<<dim3(Bn / 64, Kn / 64, Dn), 256, 0, stream>>>(x, xt, Sp);
  k_cov<<<dim3(PARTS, Kn), 64, 0, stream>>>(xt, covp);
  k_chol<<<dim3(Kn), 64, 0, stream>>>(covp, Sp, mub, wtb);
  k_solve<<<dim3(Bn / 64, Kn), 64, 0, stream>>>(xt, wtb, mub);
  k_transpose_out<<<dim3(Bn / 64, Kn / 64, Dn), 256, 0, stream>>>(xt, out);
}

// Round 2
// 512.687 us; speedup vs baseline: 1.6067x; 1.6067x over previous
//
#include <hip/hip_runtime.h>
#include <math.h>

#define Bn 4096
#define Dn 64
#define Kn 256
#define DKn (Dn * Kn)            // 16384
#define DBn ((size_t)Dn * Bn)    // 262144 elements per k-slab
#define PARTS 8
#define BPART (Bn / PARTS)       // 512
#define NBT 32                   // 4096 / 128 (K1 b-tile)

typedef __attribute__((ext_vector_type(8))) short bf16x8;
typedef __attribute__((ext_vector_type(4))) float f32x4;
typedef unsigned short ushort_t;
typedef unsigned int uint_t;

// scratch layout inside d_out (floats), consumed before K5 overwrites d_out
#define SP_OFF 0                                   // Sp[K][D][NBT]           = 524,288
#define CP_OFF (Kn * Dn * NBT)                     // covp[K][PARTS][20][256] = 10,485,760
#define MU_OFF (CP_OFF + Kn * PARTS * 20 * 256)    // mu[K][D]                = 16,384
#define WT_OFF (MU_OFF + Kn * Dn)                  // wt[K][c][i]=Linv[i][c]  = 1,048,576

__device__ __forceinline__ float bf2f(ushort_t u) {
  return __uint_as_float(((uint_t)u) << 16);
}
__device__ __forceinline__ ushort_t f2bf(float f) {  // RNE
  uint_t x = __float_as_uint(f);
  uint_t r = x + 0x7fffu + ((x >> 16) & 1u);
  return (ushort_t)(r >> 16);
}
__device__ __forceinline__ int pairidx(int m, int n) { return (m * (7 - m)) / 2 + n; }

// ---- K1: x[B,D,K] -> xh/xl[K,D,B] (bf16 hi/lo split), fused partial sums ----
__global__ __launch_bounds__(256) void k_transpose_in(
    const float* __restrict__ x, ushort_t* __restrict__ xh, ushort_t* __restrict__ xl,
    float* __restrict__ Sp) {
  __shared__ float tile[128][65];
  const int b0 = blockIdx.x * 128;
  const int k0 = blockIdx.y * 64;
  const int d = blockIdx.z;
  const int l = threadIdx.x & 63;
  const int w = threadIdx.x >> 6;
#pragma unroll
  for (int i = 0; i < 32; ++i) {
    const int row = i * 4 + w;
    tile[row][l] = x[(size_t)(b0 + row) * DKn + (size_t)d * Kn + k0 + l];
  }
  __syncthreads();
#pragma unroll
  for (int i = 0; i < 16; ++i) {
    const int kk = i * 4 + w;
    const float v0 = tile[2 * l][kk];
    const float v1 = tile[2 * l + 1][kk];
    const ushort_t h0 = f2bf(v0), h1 = f2bf(v1);
    const ushort_t l0 = f2bf(v0 - bf2f(h0)), l1 = f2bf(v1 - bf2f(h1));
    const size_t base = (size_t)(k0 + kk) * DBn + (size_t)d * Bn + b0;
    *(uint_t*)&xh[base + 2 * l] = (uint_t)h0 | ((uint_t)h1 << 16);
    *(uint_t*)&xl[base + 2 * l] = (uint_t)l0 | ((uint_t)l1 << 16);
    float s = v0 + v1;
#pragma unroll
    for (int off = 32; off > 0; off >>= 1) s += __shfl_xor(s, off, 64);
    if (l == 0) Sp[(size_t)(k0 + kk) * (Dn * NBT) + d * NBT + blockIdx.x] = s;
  }
}

// ---- K2: MFMA partial raw moments. HH = hi*hi^T, CR = hi*lo^T + lo*hi^T -----
__global__ __launch_bounds__(256) void k_cov_mfma(
    const ushort_t* __restrict__ xh, const ushort_t* __restrict__ xl,
    float* __restrict__ covp) {
  const int k = blockIdx.y;
  const int part = blockIdx.x * 4 + (threadIdx.x >> 6);
  const int lane = threadIdx.x & 63;
  const int r16 = lane & 15;
  const int kb = lane >> 4;
  const size_t kbase = (size_t)k * DBn;
  const ushort_t* ph = xh + kbase;
  const ushort_t* pl = xl + kbase;
  f32x4 hh[10], cr[10];
#pragma unroll
  for (int p = 0; p < 10; ++p) {
    hh[p] = (f32x4){0.f, 0.f, 0.f, 0.f};
    cr[p] = (f32x4){0.f, 0.f, 0.f, 0.f};
  }
  const int c0 = part * BPART + kb * 8;
  for (int s = 0; s < BPART / 32; ++s) {
    const int bc = c0 + s * 32;
    bf16x8 hf[4], lf[4];
#pragma unroll
    for (int m = 0; m < 4; ++m) {
      const size_t off = (size_t)(16 * m + r16) * Bn + bc;
      hf[m] = *(const bf16x8*)(ph + off);
      lf[m] = *(const bf16x8*)(pl + off);
    }
#pragma unroll
    for (int m = 0; m < 4; ++m)
#pragma unroll
      for (int n = m; n < 4; ++n) {
        const int p = (m * (7 - m)) / 2 + n;
        hh[p] = __builtin_amdgcn_mfma_f32_16x16x32_bf16(hf[m], hf[n], hh[p], 0, 0, 0);
        cr[p] = __builtin_amdgcn_mfma_f32_16x16x32_bf16(hf[m], lf[n], cr[p], 0, 0, 0);
        cr[p] = __builtin_amdgcn_mfma_f32_16x16x32_bf16(lf[m], hf[n], cr[p], 0, 0, 0);
      }
  }
  float* cp = covp + (size_t)(k * PARTS + part) * 20 * 256;
#pragma unroll
  for (int p = 0; p < 10; ++p)
#pragma unroll
    for (int r = 0; r < 4; ++r) {
      cp[p * 256 + (kb * 4 + r) * 16 + r16] = hh[p][r];
      cp[(10 + p) * 256 + (kb * 4 + r) * 16 + r16] = cr[p][r];
    }
}

// ---- K3: reduce partials -> cov -> Cholesky -> Linv^T, mu -------------------
__global__ __launch_bounds__(256) void k_chol(
    const float* __restrict__ covp, const float* __restrict__ Sp,
    float* __restrict__ mu, float* __restrict__ wt) {
  __shared__ float a[64][65];
  __shared__ float mus[64];
  __shared__ float colv[64];
  __shared__ float diag;
  const int k = blockIdx.x;
  const int tid = threadIdx.x;

  if (tid < 64) {
    float s = 0.f;
    const float* sp = Sp + (size_t)k * (Dn * NBT) + tid * NBT;
    for (int t = 0; t < NBT; ++t) s += sp[t];
    const float m = s * (1.f / (float)Bn);
    mus[tid] = m;
    mu[k * Dn + tid] = m;
  }
  __syncthreads();

  const float* cp = covp + (size_t)k * PARTS * 20 * 256;
  for (int idx = tid; idx < 4096; idx += 256) {
    const int i = idx >> 6, j = idx & 63;
    const int i16 = i >> 4, j16 = j >> 4, r = i & 15, c = j & 63 & 15;
    int p, off;
    if (i16 <= j16) { p = pairidx(i16, j16); off = r * 16 + c; }
    else            { p = pairidx(j16, i16); off = c * 16 + r; }
    float s = 0.f;
#pragma unroll
    for (int q = 0; q < PARTS; ++q) {
      const float* b = cp + q * 20 * 256;
      s += b[p * 256 + off] + b[(10 + p) * 256 + off];
    }
    float cv = (s - (float)Bn * mus[i] * mus[j]) * (1.f / (float)(Bn - 1));
    if (i == j) cv += 1e-4f;
    a[i][j] = cv;
  }
  __syncthreads();

  for (int j = 0; j < 64; ++j) {
    if (tid == j) diag = sqrtf(a[j][j]);
    __syncthreads();
    const float ljj = diag;
    float lij = 0.f;
    if (tid == j) a[j][j] = ljj;
    if (tid < 64 && tid > j) {
      lij = a[tid][j] / ljj;
      a[tid][j] = lij;
      colv[tid] = lij;
    }
    __syncthreads();
    if (tid < 64 && tid > j) {
      for (int e = j + 1; e <= tid; ++e) a[tid][e] -= lij * colv[e];
    }
    __syncthreads();
  }

  if (tid < 64) {
    float wv[64];
#pragma unroll
    for (int i = 0; i < 64; ++i) wv[i] = 0.f;
#pragma unroll
    for (int i = 0; i < 64; ++i) {
      float s2 = (i == tid) ? 1.f : 0.f;
#pragma unroll
      for (int j = 0; j < i; ++j) s2 -= a[i][j] * wv[j];
      wv[i] = (i >= tid) ? s2 / a[i][i] : 0.f;
    }
    float* wk = wt + (size_t)k * (Dn * Dn) + tid * Dn;
#pragma unroll
    for (int i = 0; i < 64; ++i) wk[i] = wv[i];
  }
}

// ---- K4: Z = Linv (x - mu); bf16 Z written in-place over xh -----------------
__global__ __launch_bounds__(256) void k_solve(
    ushort_t* __restrict__ xh, const ushort_t* __restrict__ xl,
    const float* __restrict__ wt, const float* __restrict__ mu) {
  __shared__ float wsh[64][68];       // wsh[e][d] = Linv[d][e]
  __shared__ ushort_t xsh[64][264];   // xc bf16 [d][b-tile 256]
  __shared__ float mus[64];
  const int k = blockIdx.y;
  const int b0 = blockIdx.x * 256;
  const int t = threadIdx.x;
  const float* wk = wt + (size_t)k * (Dn * Dn);
#pragma unroll
  for (int u = 0; u < 16; ++u) {
    const int idx = u * 256 + t;
    wsh[idx >> 6][idx & 63] = wk[idx];
  }
  if (t < 64) mus[t] = mu[k * Dn + t];
  __syncthreads();

  const int c8 = t & 31, r8 = t >> 5;
  const size_t kbase = (size_t)k * DBn;
#pragma unroll
  for (int rr = 0; rr < 8; ++rr) {
    const int row = rr * 8 + r8;
    const size_t off = kbase + (size_t)row * Bn + b0 + c8 * 8;
    const bf16x8 h = *(const bf16x8*)(xh + off);
    const bf16x8 lo = *(const bf16x8*)(xl + off);
    const float mr = mus[row];
    uint_t pk[4];
#pragma unroll
    for (int q = 0; q < 4; ++q) {
      const float f0 = bf2f((ushort_t)h[2 * q]) + bf2f((ushort_t)lo[2 * q]) - mr;
      const float f1 = bf2f((ushort_t)h[2 * q + 1]) + bf2f((ushort_t)lo[2 * q + 1]) - mr;
      pk[q] = (uint_t)f2bf(f0) | ((uint_t)f2bf(f1) << 16);
    }
    *(uint4*)&xsh[row][c8 * 8] = make_uint4(pk[0], pk[1], pk[2], pk[3]);
  }
  __syncthreads();

  const int w = t >> 6, lane = t & 63;
  const int ty = lane >> 3, tx = lane & 7;
  float acc[8][8];
#pragma unroll
  for (int i = 0; i < 8; ++i)
#pragma unroll
    for (int j = 0; j < 8; ++j) acc[i][j] = 0.f;

  for (int e = 0; e < 64; ++e) {
    const float4 w0 = *(const float4*)&wsh[e][8 * ty];
    const float4 w1 = *(const float4*)&wsh[e][8 * ty + 4];
    const float wa[8] = {w0.x, w0.y, w0.z, w0.w, w1.x, w1.y, w1.z, w1.w};
    const uint4 xr = *(const uint4*)&xsh[e][w * 64 + 8 * tx];
    float xb[8];
    xb[0] = __uint_as_float(xr.x << 16); xb[1] = __uint_as_float(xr.x & 0xffff0000u);
    xb[2] = __uint_as_float(xr.y << 16); xb[3] = __uint_as_float(xr.y & 0xffff0000u);
    xb[4] = __uint_as_float(xr.z << 16); xb[5] = __uint_as_float(xr.z & 0xffff0000u);
    xb[6] = __uint_as_float(xr.w << 16); xb[7] = __uint_as_float(xr.w & 0xffff0000u);
#pragma unroll
    for (int i = 0; i < 8; ++i)
#pragma unroll
      for (int j = 0; j < 8; ++j) acc[i][j] += wa[i] * xb[j];
  }

#pragma unroll
  for (int i = 0; i < 8; ++i) {
    const int row = 8 * ty + i;
    uint_t pk[4];
#pragma unroll
    for (int q = 0; q < 4; ++q)
      pk[q] = (uint_t)f2bf(acc[i][2 * q]) | ((uint_t)f2bf(acc[i][2 * q + 1]) << 16);
    *(uint4*)&xh[kbase + (size_t)row * Bn + b0 + w * 64 + 8 * tx] =
        make_uint4(pk[0], pk[1], pk[2], pk[3]);
  }
}

// ---- K5: zb[K,D,B] (bf16) -> out[B,D,K] (fp32) ------------------------------
__global__ __launch_bounds__(256) void k_transpose_out(
    const ushort_t* __restrict__ zb, float* __restrict__ out) {
  __shared__ ushort_t tile[64][66];
  const int b0 = blockIdx.x * 64;
  const int k0 = blockIdx.y * 64;
  const int d = blockIdx.z;
  const int t = threadIdx.x;
  {
    const int row = t >> 2, q = t & 3;
    const ushort_t* src = zb + (size_t)(k0 + row) * DBn + (size_t)d * Bn + b0 + q * 16;
#pragma unroll
    for (int j = 0; j < 8; ++j)
      *(uint_t*)&tile[row][q * 16 + 2 * j] = *(const uint_t*)&src[2 * j];
  }
  __syncthreads();
  const int l = t & 63, w = t >> 6;
#pragma unroll
  for (int i = 0; i < 16; ++i) {
    const int br = i * 4 + w;
    out[(size_t)(b0 + br) * DKn + (size_t)d * Kn + k0 + l] = bf2f(tile[l][br]);
  }
}

extern "C" void kernel_launch(void* const* d_in, const int* in_sizes, int n_in,
                              void* d_out, int out_size, void* d_ws, size_t ws_size,
                              hipStream_t stream) {
  (void)in_sizes; (void)n_in; (void)out_size;
  const float* x = (const float*)d_in[0];
  float* out = (float*)d_out;
  ushort_t* xh = (ushort_t*)d_ws;                       // [K][D][B] bf16 hi, 128 MiB
  ushort_t* xl = xh + (size_t)Kn * DBn;                 // [K][D][B] bf16 lo, 128 MiB
  if (ws_size < sizeof(ushort_t) * 2 * (size_t)Kn * DBn) return;

  float* Sp = out + SP_OFF;
  float* covp = out + CP_OFF;
  float* mub = out + MU_OFF;
  float* wtb = out + WT_OFF;

  k_transpose_in<<<dim3(Bn / 128, Kn / 64, Dn), 256, 0, stream>>>(x, xh, xl, Sp);
  k_cov_mfma<<<dim3(PARTS / 4, Kn), 256, 0, stream>>>(xh, xl, covp);
  k_chol<<<dim3(Kn), 256, 0, stream>>>(covp, Sp, mub, wtb);
  k_solve<<<dim3(Bn / 256, Kn), 256, 0, stream>>>(xh, xl, wtb, mub);
  k_transpose_out<<<dim3(Bn / 64, Kn / 64, Dn), 256, 0, stream>>>(xh, out);
}

// Round 3
// 500.921 us; speedup vs baseline: 1.6444x; 1.0235x over previous
//
#include <hip/hip_runtime.h>
#include <math.h>

#define Bn 4096
#define Dn 64
#define Kn 256
#define DKn (Dn * Kn)            // 16384
#define DBn ((size_t)Dn * Bn)    // 262144

typedef __attribute__((ext_vector_type(8))) short bf16x8;
typedef __attribute__((ext_vector_type(4))) float f32x4;
typedef unsigned short u16;
typedef unsigned int u32;

__device__ __forceinline__ float bf2f(u16 u) {
  return __uint_as_float(((u32)u) << 16);
}
__device__ __forceinline__ u16 f2bf(float f) {  // RNE
  u32 x = __float_as_uint(f);
  u32 r = x + 0x7fffu + ((x >> 16) & 1u);
  return (u16)(r >> 16);
}

// ---- K1: x[B,D,K] -> xh[K,D,B] bf16, fused fp32 partial sums ---------------
// grid (32 b-tiles of 128, 4 k-chunks of 64, 64 d), block 256
__global__ __launch_bounds__(256) void k1_transpose(
    const float* __restrict__ x, u16* __restrict__ xh, float* __restrict__ Sp) {
  __shared__ float tile[128][65];
  __shared__ float sred[16][64];
  const int b0 = blockIdx.x * 128;
  const int k0 = blockIdx.y * 64;
  const int d = blockIdx.z;
  const int t = threadIdx.x;
  const int kq = t & 15, rsub = t >> 4;
  float4 sum4 = make_float4(0.f, 0.f, 0.f, 0.f);
#pragma unroll
  for (int p = 0; p < 8; ++p) {
    const int row = p * 16 + rsub;
    const float4 v = *(const float4*)&x[(size_t)(b0 + row) * DKn + (size_t)d * Kn + k0 + 4 * kq];
    *(float4*)&tile[row][4 * kq] = v;
    sum4.x += v.x; sum4.y += v.y; sum4.z += v.z; sum4.w += v.w;
  }
  *(float4*)&sred[rsub][4 * kq] = sum4;
  __syncthreads();
  if (t < 64) {
    float s = 0.f;
#pragma unroll
    for (int r = 0; r < 16; ++r) s += sred[r][t];
    Sp[(size_t)(k0 + t) * (Dn * 32) + d * 32 + blockIdx.x] = s;
  }
  const int bg = t & 15, kof = t >> 4;
#pragma unroll
  for (int p = 0; p < 4; ++p) {
    const int k = p * 16 + kof;
    u32 pk[4];
#pragma unroll
    for (int jj = 0; jj < 4; ++jj) {
      const float f0 = tile[8 * bg + 2 * jj][k];
      const float f1 = tile[8 * bg + 2 * jj + 1][k];
      pk[jj] = (u32)f2bf(f0) | ((u32)f2bf(f1) << 16);
    }
    *(uint4*)&xh[(size_t)(k0 + k) * DBn + (size_t)d * Bn + b0 + 8 * bg] =
        make_uint4(pk[0], pk[1], pk[2], pk[3]);
  }
}

// ---- K2: MFMA partial raw moments HH = hi*hi^T (upper-tri 16x16 pairs) -----
// grid (2, 256), block 256 (4 waves = 4 parts of 512 b each)
__global__ __launch_bounds__(256) void k2_cov(
    const u16* __restrict__ xh, float* __restrict__ covp) {
  const int k = blockIdx.y;
  const int part = blockIdx.x * 4 + (threadIdx.x >> 6);
  const int lane = threadIdx.x & 63;
  const int r16 = lane & 15, kb = lane >> 4;
  const u16* ph = xh + (size_t)k * DBn;
  f32x4 hh[10];
#pragma unroll
  for (int p = 0; p < 10; ++p) hh[p] = (f32x4){0.f, 0.f, 0.f, 0.f};
  const int c0 = part * 512 + kb * 8;
  for (int s = 0; s < 16; ++s) {
    const int bc = c0 + s * 32;
    bf16x8 hf[4];
#pragma unroll
    for (int m = 0; m < 4; ++m)
      hf[m] = *(const bf16x8*)(ph + (size_t)(16 * m + r16) * Bn + bc);
#pragma unroll
    for (int m = 0; m < 4; ++m)
#pragma unroll
      for (int n = m; n < 4; ++n) {
        const int p = (m * (7 - m)) / 2 + n;
        hh[p] = __builtin_amdgcn_mfma_f32_16x16x32_bf16(hf[m], hf[n], hh[p], 0, 0, 0);
      }
  }
  float* cp = covp + (size_t)(k * 8 + part) * 2560;
#pragma unroll
  for (int p = 0; p < 10; ++p)
#pragma unroll
    for (int r = 0; r < 4; ++r)
      cp[p * 256 + (kb * 4 + r) * 16 + r16] = hh[p][r];
}

// ---- K3: reduce -> cov -> Cholesky -> Linv (bf16, row-major), mu -----------
__global__ __launch_bounds__(256) void k3_chol(
    const float* __restrict__ covp, const float* __restrict__ Sp,
    float* __restrict__ mu, u16* __restrict__ wt) {
  __shared__ float a[64][65];
  __shared__ float mus[64];
  __shared__ float colv[64];
  __shared__ float diag;
  const int k = blockIdx.x;
  const int tid = threadIdx.x;
  if (tid < 64) {
    float s = 0.f;
    const float* sp = Sp + (size_t)k * (Dn * 32) + tid * 32;
#pragma unroll
    for (int q = 0; q < 32; ++q) s += sp[q];
    const float m = s * (1.f / 4096.f);
    mus[tid] = m;
    mu[k * 64 + tid] = m;
  }
  __syncthreads();
  const float* cp = covp + (size_t)k * 8 * 2560;
  for (int idx = tid; idx < 4096; idx += 256) {
    const int i = idx >> 6, j = idx & 63;
    const int i16 = i >> 4, j16 = j >> 4, r = i & 15, c = j & 15;
    int p, off;
    if (i16 <= j16) { p = (i16 * (7 - i16)) / 2 + j16; off = r * 16 + c; }
    else            { p = (j16 * (7 - j16)) / 2 + i16; off = c * 16 + r; }
    float s = 0.f;
#pragma unroll
    for (int q = 0; q < 8; ++q) s += cp[q * 2560 + p * 256 + off];
    float cv = (s - 4096.f * mus[i] * mus[j]) * (1.f / 4095.f);
    if (i == j) cv += 1e-4f;
    a[i][j] = cv;
  }
  __syncthreads();
  for (int j = 0; j < 64; ++j) {
    if (tid == j) diag = sqrtf(a[j][j]);
    __syncthreads();
    const float ljj = diag;
    float lij = 0.f;
    if (tid == j) a[j][j] = ljj;
    if (tid < 64 && tid > j) {
      lij = a[tid][j] / ljj;
      a[tid][j] = lij;
      colv[tid] = lij;
    }
    __syncthreads();
    if (tid < 64 && tid > j)
      for (int e = j + 1; e <= tid; ++e) a[tid][e] -= lij * colv[e];
    __syncthreads();
  }
  float wv[64];
  if (tid < 64) {
#pragma unroll
    for (int i = 0; i < 64; ++i) {
      float s2 = (i == tid) ? 1.f : 0.f;
#pragma unroll
      for (int j = 0; j < i; ++j) s2 -= a[i][j] * wv[j];
      wv[i] = (i >= tid) ? s2 / a[i][i] : 0.f;
    }
  }
  __syncthreads();
  if (tid < 64) {
#pragma unroll
    for (int i = 0; i < 64; ++i) a[i][tid] = wv[i];  // a becomes Linv (row-major)
  }
  __syncthreads();
  u16* wk = wt + (size_t)k * 4096;
#pragma unroll
  for (int it = 0; it < 8; ++it) {
    const int idx = it * 256 + tid;  // dword index
    const int dd = idx >> 5, ep = idx & 31;
    const u32 pk = (u32)f2bf(a[dd][2 * ep]) | ((u32)f2bf(a[dd][2 * ep + 1]) << 16);
    *(u32*)&wk[2 * idx] = pk;
  }
}

// ---- K45: Z = Linv(x - mu) via MFMA, write fp32 out[B,D,K] directly --------
// grid (128 b-tiles of 32, 16 k-chunks of 16), block 256 (4 waves)
__global__ __launch_bounds__(256) void k45_solve_out(
    const u16* __restrict__ xh, const u16* __restrict__ wt,
    const float* __restrict__ mu, float* __restrict__ out) {
  __shared__ u16 xcT[2][32][72];     // [buf][b][e]
  __shared__ u16 zb[64][32][18];     // [d][b][kk]
  __shared__ float mus2[16][64];
  const int b0 = blockIdx.x * 32;
  const int kc0 = blockIdx.y * 16;
  const int t = threadIdx.x;
  const int w = t >> 6, l = t & 63;
  const int r16 = l & 15, h = l >> 4;
  const int e = t >> 2, bq = t & 3;

  for (int i = t; i < 16 * 64; i += 256)
    mus2[i >> 6][i & 63] = mu[(size_t)(kc0 + (i >> 6)) * 64 + (i & 63)];
  __syncthreads();

  // prologue: stage k=0
  uint4 hv = *(const uint4*)&xh[(size_t)kc0 * DBn + (size_t)e * Bn + b0 + 8 * bq];
  bf16x8 a0, a1, an0, an1;
  {
    const u16* wk = wt + (size_t)kc0 * 4096 + (size_t)(16 * w + r16) * 64 + 8 * h;
    a0 = *(const bf16x8*)(wk);
    a1 = *(const bf16x8*)(wk + 32);
  }
  {
    const float m = mus2[0][e];
    u32 wd[4] = {hv.x, hv.y, hv.z, hv.w};
#pragma unroll
    for (int jj = 0; jj < 4; ++jj) {
      xcT[0][8 * bq + 2 * jj][e] = f2bf(__uint_as_float(wd[jj] << 16) - m);
      xcT[0][8 * bq + 2 * jj + 1][e] = f2bf(__uint_as_float(wd[jj] & 0xffff0000u) - m);
    }
  }
  __syncthreads();

  int cur = 0;
  for (int kk = 0; kk < 16; ++kk) {
    uint4 hvn;
    if (kk + 1 < 16) {
      hvn = *(const uint4*)&xh[(size_t)(kc0 + kk + 1) * DBn + (size_t)e * Bn + b0 + 8 * bq];
      const u16* wk = wt + (size_t)(kc0 + kk + 1) * 4096 + (size_t)(16 * w + r16) * 64 + 8 * h;
      an0 = *(const bf16x8*)(wk);
      an1 = *(const bf16x8*)(wk + 32);
    }
    f32x4 acc0 = (f32x4){0.f, 0.f, 0.f, 0.f};
    f32x4 acc1 = (f32x4){0.f, 0.f, 0.f, 0.f};
    {
      const bf16x8 bf00 = *(const bf16x8*)&xcT[cur][r16][8 * h];
      const bf16x8 bf01 = *(const bf16x8*)&xcT[cur][16 + r16][8 * h];
      acc0 = __builtin_amdgcn_mfma_f32_16x16x32_bf16(a0, bf00, acc0, 0, 0, 0);
      acc1 = __builtin_amdgcn_mfma_f32_16x16x32_bf16(a0, bf01, acc1, 0, 0, 0);
      const bf16x8 bf10 = *(const bf16x8*)&xcT[cur][r16][32 + 8 * h];
      const bf16x8 bf11 = *(const bf16x8*)&xcT[cur][16 + r16][32 + 8 * h];
      acc0 = __builtin_amdgcn_mfma_f32_16x16x32_bf16(a1, bf10, acc0, 0, 0, 0);
      acc1 = __builtin_amdgcn_mfma_f32_16x16x32_bf16(a1, bf11, acc1, 0, 0, 0);
    }
#pragma unroll
    for (int r = 0; r < 4; ++r) {
      zb[16 * w + 4 * h + r][r16][kk] = f2bf(acc0[r]);
      zb[16 * w + 4 * h + r][16 + r16][kk] = f2bf(acc1[r]);
    }
    if (kk + 1 < 16) {
      const float m = mus2[kk + 1][e];
      u32 wd[4] = {hvn.x, hvn.y, hvn.z, hvn.w};
#pragma unroll
      for (int jj = 0; jj < 4; ++jj) {
        xcT[cur ^ 1][8 * bq + 2 * jj][e] = f2bf(__uint_as_float(wd[jj] << 16) - m);
        xcT[cur ^ 1][8 * bq + 2 * jj + 1][e] = f2bf(__uint_as_float(wd[jj] & 0xffff0000u) - m);
      }
      a0 = an0; a1 = an1;
    }
    __syncthreads();
    cur ^= 1;
  }

  // out phase: lane covers (d,b) cells, 16 consecutive k -> 64B lines
#pragma unroll
  for (int it = 0; it < 8; ++it) {
    const int cell = it * 256 + t;
    const int b = cell & 31, dd = cell >> 5;
    float fv[16];
#pragma unroll
    for (int q = 0; q < 8; ++q) {
      const u32 v = *(const u32*)&zb[dd][b][2 * q];
      fv[2 * q] = __uint_as_float(v << 16);
      fv[2 * q + 1] = __uint_as_float(v & 0xffff0000u);
    }
    float* op = &out[(size_t)(b0 + b) * DKn + (size_t)dd * Kn + kc0];
#pragma unroll
    for (int s = 0; s < 4; ++s)
      *(float4*)&op[4 * s] = make_float4(fv[4 * s], fv[4 * s + 1], fv[4 * s + 2], fv[4 * s + 3]);
  }
}

extern "C" void kernel_launch(void* const* d_in, const int* in_sizes, int n_in,
                              void* d_out, int out_size, void* d_ws, size_t ws_size,
                              hipStream_t stream) {
  (void)in_sizes; (void)n_in; (void)out_size;
  const float* x = (const float*)d_in[0];
  float* out = (float*)d_out;
  char* ws = (char*)d_ws;
  // ws layout
  const size_t XH_B = 134217728;               // u16 [K][D][B]
  const size_t SP_B = 2097152;                 // f32 [K][D][32]
  const size_t CP_B = 20971520;                // f32 [K][8][2560]
  const size_t MU_B = 65536;                   // f32 [K][64]
  if (ws_size < XH_B + SP_B + CP_B + MU_B + 2097152) return;
  u16* xh = (u16*)ws;
  float* Sp = (float*)(ws + XH_B);
  float* covp = (float*)(ws + XH_B + SP_B);
  float* mub = (float*)(ws + XH_B + SP_B + CP_B);
  u16* wtb = (u16*)(ws + XH_B + SP_B + CP_B + MU_B);

  k1_transpose<<<dim3(32, 4, 64), 256, 0, stream>>>(x, xh, Sp);
  k2_cov<<<dim3(2, 256), 256, 0, stream>>>(xh, covp);
  k3_chol<<<dim3(256), 256, 0, stream>>>(covp, Sp, mub, wtb);
  k45_solve_out<<<dim3(128, 16), 256, 0, stream>>>(xh, wtb, mub, out);
}

// Round 4
// 376.771 us; speedup vs baseline: 2.1863x; 1.3295x over previous
//
#include <hip/hip_runtime.h>
#include <math.h>

#define Bn 4096
#define Dn 64
#define Kn 256
#define DKn 16384
#define SLAB ((size_t)262144)   // per-k slab in xh: Bn*Dn

typedef __attribute__((ext_vector_type(8))) short bf16x8;
typedef __attribute__((ext_vector_type(4))) float f32x4;
typedef unsigned short u16;
typedef unsigned int u32;

__device__ __forceinline__ float bf2f(u16 u) {
  return __uint_as_float(((u32)u) << 16);
}
__device__ __forceinline__ u16 f2bf(float f) {  // RNE
  u32 x = __float_as_uint(f);
  u32 r = x + 0x7fffu + ((x >> 16) & 1u);
  return (u16)(r >> 16);
}

// ---- K1: x[B,D,K] fp32 -> xh[k][b][d] bf16 ---------------------------------
// grid (512 b-tiles of 8, 4 k-tiles of 64), block 256
__global__ __launch_bounds__(256) void k1_transpose(
    const float* __restrict__ x, u16* __restrict__ xh) {
  __shared__ __align__(16) u16 tile[64][72];
  const int b0 = blockIdx.x * 8;
  const int k0 = blockIdx.y * 64;
  const int t = threadIdx.x;
  const int kq = t & 15, dsub = t >> 4;  // stage: float4 along k, 16 d-rows/iter
  const int kr = t >> 3, dq = t & 7;     // out: 32 k-rows/iter, 8 d-chunks

  for (int bb = 0; bb < 8; ++bb) {
    const int b = b0 + bb;
#pragma unroll
    for (int i = 0; i < 4; ++i) {
      const int d = dsub + 16 * i;
      const float4 v = *(const float4*)&x[(size_t)b * DKn + (size_t)d * Kn + k0 + 4 * kq];
      tile[4 * kq + 0][d] = f2bf(v.x);
      tile[4 * kq + 1][d] = f2bf(v.y);
      tile[4 * kq + 2][d] = f2bf(v.z);
      tile[4 * kq + 3][d] = f2bf(v.w);
    }
    __syncthreads();
#pragma unroll
    for (int it = 0; it < 2; ++it) {
      const int k = kr + 32 * it;
      const uint4 wv = *(const uint4*)&tile[k][8 * dq];
      *(uint4*)&xh[(size_t)(k0 + k) * SLAB + (size_t)b * 64 + 8 * dq] = wv;
    }
    __syncthreads();
  }
}

// ---- K2: raw moments partials via MFMA + mean partial sums -----------------
// grid (4 parts of 1024 b, 256 k), block 256 (4 waves; wave w = b-strip 32w)
__global__ __launch_bounds__(256) void k2_cov(
    const u16* __restrict__ xh, float* __restrict__ covp, float* __restrict__ Sp) {
  __shared__ __align__(16) u16 tile[64][136];  // tile[d][b] transposed stage
  __shared__ float sred[32][64];
  const int part = blockIdx.x;
  const int k = blockIdx.y;
  const int t = threadIdx.x;
  const int w = t >> 6, l = t & 63;
  const int r16 = l & 15, g = l >> 4;
  const int dw = t & 7, bq = t >> 3;
  const u16* pk = xh + (size_t)k * SLAB;

  f32x4 hh[10];
#pragma unroll
  for (int p = 0; p < 10; ++p) hh[p] = (f32x4){0.f, 0.f, 0.f, 0.f};
  float sums[8];
#pragma unroll
  for (int jj = 0; jj < 8; ++jj) sums[jj] = 0.f;

  for (int sub = 0; sub < 8; ++sub) {
    const int bbase = part * 1024 + sub * 128;
    __syncthreads();
#pragma unroll
    for (int i = 0; i < 4; ++i) {
      const int b = bq * 4 + i;
      const uint4 v = *(const uint4*)&pk[(size_t)(bbase + b) * 64 + dw * 8];
      const u16* pv = (const u16*)&v;
#pragma unroll
      for (int jj = 0; jj < 8; ++jj) {
        const u16 h = pv[jj];
        sums[jj] += bf2f(h);
        tile[dw * 8 + jj][b] = h;
      }
    }
    __syncthreads();
    bf16x8 fr[4];
#pragma unroll
    for (int m = 0; m < 4; ++m)
      fr[m] = *(const bf16x8*)&tile[16 * m + r16][32 * w + 8 * g];
#pragma unroll
    for (int m = 0; m < 4; ++m)
#pragma unroll
      for (int n = m; n < 4; ++n) {
        const int p = (m * (7 - m)) / 2 + n;
        hh[p] = __builtin_amdgcn_mfma_f32_16x16x32_bf16(fr[m], fr[n], hh[p], 0, 0, 0);
      }
  }
  // deterministic: 16 partials per k (part*4 + wave)
  float* cp = covp + ((size_t)k * 16 + part * 4 + w) * 2560;
#pragma unroll
  for (int p = 0; p < 10; ++p)
#pragma unroll
    for (int r = 0; r < 4; ++r)
      cp[p * 256 + (g * 4 + r) * 16 + r16] = hh[p][r];
  // mean partials
#pragma unroll
  for (int jj = 0; jj < 8; ++jj) sred[bq][dw * 8 + jj] = sums[jj];
  __syncthreads();
  if (t < 64) {
    float s = 0.f;
#pragma unroll
    for (int q = 0; q < 32; ++q) s += sred[q][t];
    Sp[((size_t)k * 4 + part) * 64 + t] = s;
  }
}

// ---- K3: reduce -> cov -> Cholesky -> Linv (bf16 row-major) + v = Linv*mu --
__global__ __launch_bounds__(256) void k3_chol(
    const float* __restrict__ covp, const float* __restrict__ Sp,
    u16* __restrict__ wt, u16* __restrict__ vout) {
  __shared__ float a[64][65];
  __shared__ float mus[64];
  __shared__ float colv[64];
  __shared__ float diag;
  const int k = blockIdx.x;
  const int tid = threadIdx.x;
  if (tid < 64) {
    float s = 0.f;
#pragma unroll
    for (int q = 0; q < 4; ++q) s += Sp[((size_t)k * 4 + q) * 64 + tid];
    mus[tid] = s * (1.f / 4096.f);
  }
  __syncthreads();
  const float* cp = covp + (size_t)k * 16 * 2560;
  for (int idx = tid; idx < 4096; idx += 256) {
    const int i = idx >> 6, j = idx & 63;
    const int i16 = i >> 4, j16 = j >> 4, r = i & 15, c = j & 15;
    int p, off;
    if (i16 <= j16) { p = (i16 * (7 - i16)) / 2 + j16; off = r * 16 + c; }
    else            { p = (j16 * (7 - j16)) / 2 + i16; off = c * 16 + r; }
    float s = 0.f;
#pragma unroll
    for (int q = 0; q < 16; ++q) s += cp[q * 2560 + p * 256 + off];
    float cv = (s - 4096.f * mus[i] * mus[j]) * (1.f / 4095.f);
    if (i == j) cv += 1e-4f;
    a[i][j] = cv;
  }
  __syncthreads();
  for (int j = 0; j < 64; ++j) {
    if (tid == j) diag = sqrtf(a[j][j]);
    __syncthreads();
    const float ljj = diag;
    float lij = 0.f;
    if (tid == j) a[j][j] = ljj;
    if (tid < 64 && tid > j) {
      lij = a[tid][j] / ljj;
      a[tid][j] = lij;
      colv[tid] = lij;
    }
    __syncthreads();
    if (tid < 64 && tid > j)
      for (int e = j + 1; e <= tid; ++e) a[tid][e] -= lij * colv[e];
    __syncthreads();
  }
  float wv[64];
  if (tid < 64) {
#pragma unroll
    for (int i = 0; i < 64; ++i) {
      float s2 = (i == tid) ? 1.f : 0.f;
#pragma unroll
      for (int j = 0; j < i; ++j) s2 -= a[i][j] * wv[j];
      wv[i] = (i >= tid) ? s2 / a[i][i] : 0.f;
    }
  }
  __syncthreads();
  if (tid < 64) {
#pragma unroll
    for (int i = 0; i < 64; ++i) a[i][tid] = wv[i];  // a = Linv row-major
  }
  __syncthreads();
  if (tid < 64) {
    float v = 0.f;
#pragma unroll
    for (int e = 0; e < 64; ++e) v += a[tid][e] * mus[e];
    vout[(size_t)k * 64 + tid] = f2bf(v);
  }
#pragma unroll
  for (int it = 0; it < 8; ++it) {
    const int idx = it * 256 + tid;
    const int dd = idx >> 5, ep = idx & 31;
    const u32 pk2 = (u32)f2bf(a[dd][2 * ep]) | ((u32)f2bf(a[dd][2 * ep + 1]) << 16);
    *(u32*)&wt[(size_t)k * 4096 + 2 * idx] = pk2;
  }
}

// ---- K45: Z = Linv*x - v via MFMA, fp32 out[B,D,K] with full-line writes ---
// grid (256 b-tiles of 16, 8 k-chunks of 32), block 256 (4 waves = d-quarters)
__global__ __launch_bounds__(256) void k45_solve(
    const u16* __restrict__ xh, const u16* __restrict__ wt,
    const u16* __restrict__ vin, float* __restrict__ out) {
  __shared__ __align__(16) u16 xstage[2][16][64];  // [k-of-round][b][d]
  __shared__ u16 zb[64][16][34];                   // [d][b][k]
  __shared__ __align__(16) u16 vsh[32][64];        // [k][d]
  const int b0 = blockIdx.x * 16;
  const int kc0 = blockIdx.y * 32;
  const int t = threadIdx.x;
  const int w = t >> 6, l = t & 63;
  const int r16 = l & 15, g = l >> 4;
  const int skl = t >> 7, sb = (t & 127) >> 3, sdq = t & 7;

  {
    const uint4 vv = *(const uint4*)&vin[(size_t)kc0 * 64 + t * 8];
    *(uint4*)&((u16*)vsh)[t * 8] = vv;
  }

  bf16x8 ac00, ac01, ac10, ac11, an00, an01, an10, an11;
  uint4 scur, snext;
  {
    const int k = kc0 + skl;
    scur = *(const uint4*)&xh[(size_t)k * SLAB + (size_t)(b0 + sb) * 64 + sdq * 8];
    const u16* wk0 = wt + (size_t)kc0 * 4096 + (16 * w + r16) * 64 + 8 * g;
    ac00 = *(const bf16x8*)(wk0);
    ac01 = *(const bf16x8*)(wk0 + 32);
    const u16* wk1 = wk0 + 4096;
    ac10 = *(const bf16x8*)(wk1);
    ac11 = *(const bf16x8*)(wk1 + 32);
  }

  for (int rnd = 0; rnd < 16; ++rnd) {
    if (rnd + 1 < 16) {
      const int k = kc0 + (rnd + 1) * 2 + skl;
      snext = *(const uint4*)&xh[(size_t)k * SLAB + (size_t)(b0 + sb) * 64 + sdq * 8];
      const u16* wk0 = wt + (size_t)(kc0 + (rnd + 1) * 2) * 4096 + (16 * w + r16) * 64 + 8 * g;
      an00 = *(const bf16x8*)(wk0);
      an01 = *(const bf16x8*)(wk0 + 32);
      const u16* wk1 = wk0 + 4096;
      an10 = *(const bf16x8*)(wk1);
      an11 = *(const bf16x8*)(wk1 + 32);
    }
    *(uint4*)&xstage[skl][sb][sdq * 8] = scur;
    __syncthreads();
#pragma unroll
    for (int kl = 0; kl < 2; ++kl) {
      const int k = rnd * 2 + kl;
      const bf16x8 bf0 = *(const bf16x8*)&xstage[kl][r16][8 * g];
      const bf16x8 bf1 = *(const bf16x8*)&xstage[kl][r16][32 + 8 * g];
      f32x4 acc = (f32x4){0.f, 0.f, 0.f, 0.f};
      if (kl == 0) {
        acc = __builtin_amdgcn_mfma_f32_16x16x32_bf16(ac00, bf0, acc, 0, 0, 0);
        acc = __builtin_amdgcn_mfma_f32_16x16x32_bf16(ac01, bf1, acc, 0, 0, 0);
      } else {
        acc = __builtin_amdgcn_mfma_f32_16x16x32_bf16(ac10, bf0, acc, 0, 0, 0);
        acc = __builtin_amdgcn_mfma_f32_16x16x32_bf16(ac11, bf1, acc, 0, 0, 0);
      }
#pragma unroll
      for (int r = 0; r < 4; ++r)
        zb[16 * w + 4 * g + r][r16][k] = f2bf(acc[r]);
    }
    scur = snext;
    ac00 = an00; ac01 = an01; ac10 = an10; ac11 = an11;
    __syncthreads();
  }

  // out: thread (w,l) iter it -> cell (d=l, b=4w+it), 128B per cell
#pragma unroll
  for (int it = 0; it < 4; ++it) {
    const int b = 4 * w + it;
    const int d = l;
    float* op = &out[(size_t)(b0 + b) * DKn + (size_t)d * Kn + kc0];
#pragma unroll
    for (int q = 0; q < 8; ++q) {
      float4 ov;
      ov.x = bf2f(zb[d][b][4 * q + 0]) - bf2f(vsh[4 * q + 0][d]);
      ov.y = bf2f(zb[d][b][4 * q + 1]) - bf2f(vsh[4 * q + 1][d]);
      ov.z = bf2f(zb[d][b][4 * q + 2]) - bf2f(vsh[4 * q + 2][d]);
      ov.w = bf2f(zb[d][b][4 * q + 3]) - bf2f(vsh[4 * q + 3][d]);
      *(float4*)&op[4 * q] = ov;
    }
  }
}

extern "C" void kernel_launch(void* const* d_in, const int* in_sizes, int n_in,
                              void* d_out, int out_size, void* d_ws, size_t ws_size,
                              hipStream_t stream) {
  (void)in_sizes; (void)n_in; (void)out_size;
  const float* x = (const float*)d_in[0];
  float* out = (float*)d_out;
  char* ws = (char*)d_ws;
  const size_t XH_B = 134217728;   // u16 [256][4096][64]
  const size_t CP_B = 41943040;    // f32 [256][16][2560]
  const size_t SP_B = 262144;      // f32 [256][4][64]
  const size_t WT_B = 2097152;     // u16 [256][64][64]
  const size_t V_B  = 32768;       // u16 [256][64]
  if (ws_size < XH_B + CP_B + SP_B + WT_B + V_B) return;
  u16* xh = (u16*)ws;
  float* covp = (float*)(ws + XH_B);
  float* Sp = (float*)(ws + XH_B + CP_B);
  u16* wtb = (u16*)(ws + XH_B + CP_B + SP_B);
  u16* vb  = (u16*)(ws + XH_B + CP_B + SP_B + WT_B);

  k1_transpose<<<dim3(512, 4), 256, 0, stream>>>(x, xh);
  k2_cov<<<dim3(4, 256), 256, 0, stream>>>(xh, covp, Sp);
  k3_chol<<<dim3(256), 256, 0, stream>>>(covp, Sp, wtb, vb);
  k45_solve<<<dim3(256, 8), 256, 0, stream>>>(xh, wtb, vb, out);
}